// Round 9
// baseline (19976.154 us; speedup 1.0000x reference)
//
#include <hip/hip_runtime.h>
#include <math.h>

#define EOS_TOK 1
#define SOS_TOK 2

#define Bn 32
#define Hn 512
#define En 256
#define Vn 32000
#define G3H 1536                 // 3*H
#define NROWS (Vn + G3H)         // 33536 = 256*131
#define NBLK 256                 // 1 block/CU
#define NTHR 1024                // 16 waves
#define RPB 131                  // rows per block
#define TPK 9                    // 16-row tiles per kh half (144 row slots)
#define NT2 18                   // total tile phases per step (9 x 2 kh)
#define GHPB 6                   // gh rows per block in pre-pass

typedef unsigned long long ull;

// ---- relaxed agent-scope (device-coherent) accessors ----
template <typename T>
__device__ __forceinline__ T ldA(const T* p) {
    return __hip_atomic_load(p, __ATOMIC_RELAXED, __HIP_MEMORY_SCOPE_AGENT);
}
template <typename T>
__device__ __forceinline__ void stA(T* p, T v) {
    __hip_atomic_store(p, v, __ATOMIC_RELAXED, __HIP_MEMORY_SCOPE_AGENT);
}

// ---- workspace layout ----
// [0,192K): gh  [192K,196K): pad [196K,200K): slots  [200K..): done  [256K..): 65 h buffers (64KB)
struct WS { float* gh; ull* slots; int* done; float* hb; };
__device__ __forceinline__ WS get_ws(void* ws) {
    WS w;
    w.gh    = (float*)ws;
    w.slots = (ull*)((char*)ws + 196608);
    w.done  = (int*)((char*)ws + 196608 + 4096);
    w.hb    = (float*)((char*)ws + 262144);
    return w;
}
#define HBUF(w, k) ((w).hb + (size_t)(k) * (Bn * Hn))
// tiled h layout: float index of h[b][col] = (col>>2)*128 + b*4 + (col&3)  (= float4 [col4][b])
__device__ __forceinline__ int h_idx(int b, int col) {
    return ((col >> 2) << 7) + (b << 2) + (col & 3);
}

// ---- fence-free grid barrier ----
struct PadCnt { ull v; ull pad[7]; };
__device__ PadCnt g_leaf[32];
__device__ ull    g_release;

__device__ __forceinline__ void grid_barrier(int bid) {
    __syncthreads();
    if (threadIdx.x == 0) {
        __builtin_amdgcn_s_waitcnt(0);
        ull my = __hip_atomic_fetch_add(&g_leaf[bid >> 3].v, 1ull,
                                        __ATOMIC_RELAXED, __HIP_MEMORY_SCOPE_AGENT) + 1;
        ull k = (my + 7) >> 3;
        if (bid == 0) {
            ull need = k << 3;
            for (;;) {
                bool again = false;
                #pragma unroll
                for (int i = 0; i < 32; ++i)
                    again |= (ldA(&g_leaf[i].v) < need);
                if (!again) break;
                __builtin_amdgcn_s_sleep(1);
            }
            stA(&g_release, k);
        } else {
            while (ldA(&g_release) < k) __builtin_amdgcn_s_sleep(2);
        }
        __asm__ __volatile__("" ::: "memory");
    }
    __syncthreads();
}

__device__ __forceinline__ unsigned int fkey(float f) {
    unsigned int b = __float_as_uint(f);
    return (b & 0x80000000u) ? ~b : (b | 0x80000000u);
}

// ---- async DMA: wave wv stages tile-row wv's kh-half (1 KB) in ONE inst ----
__device__ __forceinline__ void issue_tile(
    int j, char* smem, int bid, int wv, int lane,
    const float* __restrict__ W_proj, const float* __restrict__ W_hh)
{
    int jj = (j < TPK) ? j : j - TPK;
    int kh = (j < TPK) ? 0 : 1;
    int rl = jj * 16 + wv;
    int r  = bid * RPB + rl;
    if (rl >= RPB) r = 0;                    // pad rows: dummy, skipped in epilogue
    const float* base = (r < Vn) ? (W_proj + (size_t)r * Hn)
                                 : (W_hh   + (size_t)(r - Vn) * Hn);
    const float* g = base + kh * 256 + lane * 4;
    char* l = smem + (j & 1) * 16384 + wv * 1024;
    __builtin_amdgcn_global_load_lds((const __attribute__((address_space(1))) void*)g,
                                     (__attribute__((address_space(3))) void*)l, 16, 0, 0);
}

// stage h kh-half (32 KB) into LDS [k4loc][b] float4 layout (plain cached loads:
// fresh write-once buffer, first touch this launch -> no stale-L1 hazard; R8-verified)
__device__ __forceinline__ void stage_h(char* smem, const float* __restrict__ hcur,
                                        int kh, int tid) {
    float4* dst = (float4*)(smem + 32768);
    const float4* src = (const float4*)hcur + kh * 2048;
    dst[tid]        = src[tid];
    dst[tid + 1024] = src[tid + 1024];
}

// ---------------- Phase B: dual-LDS DMA-pipelined logits + gh + argmax -------------
__device__ __forceinline__ void phase_b(
    int tid, int bid, int t,
    const float* __restrict__ W_proj, const float* __restrict__ W_hh,
    const float* __restrict__ b_proj, const float* __restrict__ b_hh,
    const float* __restrict__ hcur, float* __restrict__ ws_gh,
    ull* __restrict__ slots, char* smem)
{
    const int lane = tid & 63, wv = tid >> 6;
    const int b = lane & 31, rh = lane >> 5;
    const int s = wv & 3, ksub = wv >> 2;

    issue_tile(0, smem, bid, wv, lane, W_proj, W_hh);
    issue_tile(1, smem, bid, wv, lane, W_proj, W_hh);
    stage_h(smem, hcur, 0, tid);
    __syncthreads();

    float accx[TPK][2], accy[TPK][2];
    #pragma unroll
    for (int i = 0; i < TPK; ++i) {
        accx[i][0] = accx[i][1] = 0.f;
        accy[i][0] = accy[i][1] = 0.f;
    }

    #pragma unroll
    for (int kh = 0; kh < 2; ++kh) {
        if (kh == 1) {                       // all waves past barrier-B of tile 8
            stage_h(smem, hcur, 1, tid);
            __syncthreads();
        }
        #pragma unroll
        for (int jj = 0; jj < TPK; ++jj) {
            const int j = kh * TPK + jj;
            if (j < NT2 - 1) asm volatile("s_waitcnt vmcnt(1)" ::: "memory");
            else             asm volatile("s_waitcnt vmcnt(0)" ::: "memory");
            __builtin_amdgcn_s_barrier();    // tile j landed for all waves

            const float4* wt  = (const float4*)(smem + (j & 1) * 16384);
            const float4* w0p = wt + (size_t)(4 * s + 2 * rh) * 64 + ksub * 16;
            const float4* w1p = w0p + 64;
            const float4* hl  = (const float4*)(smem + 32768) + ksub * 16 * 32 + b;

            #pragma unroll
            for (int e = 0; e < 16; ++e) {
                float4 h4 = hl[e * 32];      // 32-distinct, 2-way bcast
                float4 w0 = w0p[e];          // 2-addr bcast
                float4 w1 = w1p[e];
                accx[jj][0] = fmaf(h4.x, w0.x, accx[jj][0]);
                accy[jj][0] = fmaf(h4.y, w0.y, accy[jj][0]);
                accx[jj][0] = fmaf(h4.z, w0.z, accx[jj][0]);
                accy[jj][0] = fmaf(h4.w, w0.w, accy[jj][0]);
                accx[jj][1] = fmaf(h4.x, w1.x, accx[jj][1]);
                accy[jj][1] = fmaf(h4.y, w1.y, accy[jj][1]);
                accx[jj][1] = fmaf(h4.z, w1.z, accx[jj][1]);
                accy[jj][1] = fmaf(h4.w, w1.w, accy[jj][1]);
            }
            __builtin_amdgcn_s_barrier();    // all reads of buf (j&1) done
            if (j + 2 < NT2)
                issue_tile(j + 2, smem, bid, wv, lane, W_proj, W_hh);
        }
    }
    __syncthreads();                         // tiles + h dead; reuse LDS

    float acc[TPK][2];
    #pragma unroll
    for (int i = 0; i < TPK; ++i) {
        acc[i][0] = accx[i][0] + accy[i][0];
        acc[i][1] = accx[i][1] + accy[i][1];
    }

    // combine 4 k-quarter partials (ksub classes) via LDS tree -> ksub 0
    float* A  = (float*)smem;                // 18 KB
    float* Bs = (float*)(smem + 18432);      // 18 KB
    ull*   red = (ull*)(smem + 36864);       // 2 KB
    #define ROWL(t2, j2) (16 * (t2) + 4 * s + 2 * rh + (j2))

    if (ksub == 1 || ksub == 3) {
        float* dst = (ksub == 1) ? A : Bs;
        #pragma unroll
        for (int t2 = 0; t2 < TPK; ++t2) {
            dst[ROWL(t2, 0) * 32 + b] = acc[t2][0];
            dst[ROWL(t2, 1) * 32 + b] = acc[t2][1];
        }
    }
    __syncthreads();
    if (ksub == 0 || ksub == 2) {
        const float* srcp = (ksub == 0) ? A : Bs;
        #pragma unroll
        for (int t2 = 0; t2 < TPK; ++t2) {
            acc[t2][0] += srcp[ROWL(t2, 0) * 32 + b];
            acc[t2][1] += srcp[ROWL(t2, 1) * 32 + b];
        }
    }
    __syncthreads();
    if (ksub == 2) {
        #pragma unroll
        for (int t2 = 0; t2 < TPK; ++t2) {
            A[ROWL(t2, 0) * 32 + b] = acc[t2][0];
            A[ROWL(t2, 1) * 32 + b] = acc[t2][1];
        }
    }
    __syncthreads();
    if (ksub == 0) {
        ull best = 0ull;
        #pragma unroll
        for (int t2 = 0; t2 < TPK; ++t2) {
            #pragma unroll
            for (int j2 = 0; j2 < 2; ++j2) {
                int rl = ROWL(t2, j2);
                float tot = acc[t2][j2] + A[rl * 32 + b];
                if (rl < RPB) {
                    int r = bid * RPB + rl;
                    if (r < Vn) {
                        float v = tot + b_proj[r];
                        ull pk = ((ull)fkey(v) << 32) | (unsigned int)(~(unsigned int)r);
                        if (pk > best) best = pk;   // ties: smaller r wins via ~r
                    } else {
                        stA(&ws_gh[(size_t)b * G3H + (r - Vn)], tot + b_hh[r - Vn]);
                    }
                }
            }
        }
        red[((wv << 1) | rh) * 32 + b] = best;      // wv in [0,4) here
    }
    __syncthreads();
    if (tid < Bn) {
        ull m = red[tid];
        #pragma unroll
        for (int s2 = 1; s2 < 8; ++s2) {
            ull v = red[(s2 << 5) + tid];
            if (v > m) m = v;
        }
        if (m != 0ull)
            atomicMax(&slots[((size_t)(t & 1) * 8 + (bid & 7)) * Bn + tid], m);
    }
    #undef ROWL
}

// ---------------- pre-pass: gh(h0) only (6 rows/block), plain loads ----------------
__device__ __forceinline__ void phase_b_pre(
    int tid, int bid,
    const float* __restrict__ W_hh, const float* __restrict__ b_hh,
    const float* __restrict__ h0, float* __restrict__ ws_gh, char* smem)
{
    const int g = tid >> 5, b = tid & 31;
    const int row6 = g >> 1, kh = g & 1;
    const bool act = g < 12;
    float* scratch = (float*)smem;
    float a = 0.f;
    int rglob = bid * GHPB + row6;
    if (act) {
        const float4* wr = (const float4*)(W_hh + (size_t)rglob * Hn) + kh * 64;
        const float4* hb = ((const float4*)h0) + (size_t)(kh * 64) * 32 + b;
        float a0 = 0.f, a1 = 0.f;
        #pragma unroll 4
        for (int e = 0; e < 64; ++e) {
            float4 w4 = wr[e];
            float4 h4 = hb[(size_t)e * 32];
            a0 = fmaf(h4.x, w4.x, a0);
            a1 = fmaf(h4.y, w4.y, a1);
            a0 = fmaf(h4.z, w4.z, a0);
            a1 = fmaf(h4.w, w4.w, a1);
        }
        a = a0 + a1;
    }
    if (act && kh == 1) scratch[row6 * Bn + b] = a;
    __syncthreads();
    if (act && kh == 0)
        stA(&ws_gh[(size_t)b * G3H + rglob], a + scratch[row6 * Bn + b] + b_hh[rglob]);
}

// ---------------- Phase A: token resolve + embed/gx + gate combine + h update -------
__device__ __forceinline__ void phase_a(
    int tid, int bid, int t, int T,
    const float* __restrict__ emb, const float* __restrict__ W_ih,
    const float* __restrict__ b_ih,
    const float* __restrict__ hold_, float* __restrict__ hnew,
    const float* __restrict__ ws_gh,
    ull* __restrict__ slots, int* __restrict__ done,
    int* __restrict__ out, char* smem)
{
    int* s_tok = (int*)smem;
    float* s_gx = (float*)(smem + 128);

    if (tid < Bn) {
        int b = tid;
        int tok, dnew;
        if (t == 0) { tok = SOS_TOK; dnew = 0; }
        else {
            const ull* sl = slots + (size_t)((t - 1) & 1) * (8 * Bn);
            ull m = ldA(&sl[b]);
            #pragma unroll
            for (int s = 1; s < 8; ++s) {
                ull v = ldA(&sl[s * Bn + b]);
                if (v > m) m = v;
            }
            int idx = (int)(~(unsigned int)m);
            int dold = ldA(&done[((t - 1) & 1) * Bn + b]);
            tok  = dold ? EOS_TOK : idx;
            dnew = dold | (idx == EOS_TOK);
        }
        s_tok[b] = tok;
        if (bid == 0) {
            stA(&done[(t & 1) * Bn + b], dnew);
            if (t > 0) out[(size_t)(t - 1) * Bn + b] = tok;
            ull* sr = slots + (size_t)(t & 1) * (8 * Bn);
            #pragma unroll
            for (int s = 0; s < 8; ++s) stA(&sr[s * Bn + b], 0ull);
        }
    }
    __syncthreads();
    if (t >= T) return;

    if (tid < 768) {
        int d    = tid >> 2;
        int q    = tid & 3;
        int b    = d & 31;
        int rem  = d >> 5;
        int gate = rem >> 1;
        int ci   = rem & 1;
        int col  = bid + (ci << 8);
        const float* wrow = W_ih + (size_t)(gate * Hn + col) * En + q * (En / 4);
        const float* xrow = emb + (size_t)s_tok[b] * En + q * (En / 4);
        float ax = 0.f, ay = 0.f;
        #pragma unroll
        for (int e4 = 0; e4 < En / 16; ++e4) {
            float4 w4 = *(const float4*)(wrow + 4 * e4);
            float4 x4 = *(const float4*)(xrow + 4 * e4);
            ax = fmaf(x4.x, w4.x, ax);
            ay = fmaf(x4.y, w4.y, ay);
            ax = fmaf(x4.z, w4.z, ax);
            ay = fmaf(x4.w, w4.w, ay);
        }
        float a = ax + ay;
        a += __shfl_xor(a, 1);
        a += __shfl_xor(a, 2);
        if (q == 0) s_gx[(ci * 3 + gate) * Bn + b] = a;
    }
    __syncthreads();

    if (tid < 64) {
        int b   = tid & 31;
        int ci  = tid >> 5;
        int col = bid + (ci << 8);
        float gxr = s_gx[(ci * 3 + 0) * Bn + b] + b_ih[col];
        float gxz = s_gx[(ci * 3 + 1) * Bn + b] + b_ih[Hn + col];
        float gxn = s_gx[(ci * 3 + 2) * Bn + b] + b_ih[2 * Hn + col];
        const float* ghrow = ws_gh + (size_t)b * G3H;
        float ghr = ldA(&ghrow[col]);
        float ghz = ldA(&ghrow[Hn + col]);
        float ghn = ldA(&ghrow[2 * Hn + col]);
        float r = 1.0f / (1.0f + expf(-(gxr + ghr)));
        float z = 1.0f / (1.0f + expf(-(gxz + ghz)));
        float n = tanhf(gxn + r * ghn);
        int ti = h_idx(b, col);
        float hold = hold_[ti];
        stA(&hnew[ti], (1.0f - z) * n + z * hold);
    }
}

// ================= cooperative single-kernel path =================
__global__ void __launch_bounds__(NTHR, 4)
decode_coop(const float* __restrict__ hidden, const float* __restrict__ emb,
            const float* __restrict__ W_ih, const float* __restrict__ W_hh,
            const float* __restrict__ b_ih, const float* __restrict__ b_hh,
            const float* __restrict__ W_proj, const float* __restrict__ b_proj,
            const int* __restrict__ max_len_p, int* __restrict__ out, void* ws_raw)
{
    const int tid = threadIdx.x, bid = blockIdx.x;
    __shared__ char smem[65536];
    WS w = get_ws(ws_raw);
    const int T = max_len_p[0];

    for (int i = bid * NTHR + tid; i < Bn * Hn; i += NBLK * NTHR) {
        int b = i >> 9, col = i & (Hn - 1);
        stA(HBUF(w, 0) + h_idx(b, col), hidden[i]);
    }
    grid_barrier(bid);

    phase_b_pre(tid, bid, W_hh, b_hh, HBUF(w, 0), w.gh, smem);
    grid_barrier(bid);

    for (int t = 0; t < T; ++t) {
        phase_a(tid, bid, t, T, emb, W_ih, b_ih, HBUF(w, t), HBUF(w, t + 1),
                w.gh, w.slots, w.done, out, smem);
        grid_barrier(bid);
        phase_b(tid, bid, t, W_proj, W_hh, b_proj, b_hh, HBUF(w, t + 1),
                w.gh, w.slots, smem);
        grid_barrier(bid);
    }
    phase_a(tid, bid, T, T, emb, W_ih, b_ih, HBUF(w, T), HBUF(w, 64),
            w.gh, w.slots, w.done, out, smem);
}

// ================= non-cooperative fallback path =================
__global__ void __launch_bounds__(NTHR)
k_init(const float* __restrict__ hidden, void* ws_raw) {
    WS w = get_ws(ws_raw);
    int i = blockIdx.x * NTHR + threadIdx.x;
    if (i < Bn * Hn) {
        int b = i >> 9, col = i & (Hn - 1);
        stA(HBUF(w, 0) + h_idx(b, col), hidden[i]);
    }
}

__global__ void __launch_bounds__(NTHR, 4)
k_pre(const float* __restrict__ W_hh, const float* __restrict__ b_hh, void* ws_raw) {
    __shared__ char smem[65536];
    WS w = get_ws(ws_raw);
    phase_b_pre(threadIdx.x, blockIdx.x, W_hh, b_hh, HBUF(w, 0), w.gh, smem);
}

__global__ void __launch_bounds__(NTHR, 4)
k_b(int t, const int* __restrict__ max_len_p,
    const float* __restrict__ W_proj, const float* __restrict__ W_hh,
    const float* __restrict__ b_proj, const float* __restrict__ b_hh, void* ws_raw)
{
    if (t >= max_len_p[0]) return;
    __shared__ char smem[65536];
    WS w = get_ws(ws_raw);
    phase_b(threadIdx.x, blockIdx.x, t, W_proj, W_hh, b_proj, b_hh,
            HBUF(w, t + 1), w.gh, w.slots, smem);
}

__global__ void __launch_bounds__(NTHR, 4)
k_a(int t, const int* __restrict__ max_len_p,
    const float* __restrict__ emb, const float* __restrict__ W_ih,
    const float* __restrict__ b_ih, int* __restrict__ out, void* ws_raw)
{
    int T = max_len_p[0];
    if (t > T) return;
    __shared__ char smem[65536];
    WS w = get_ws(ws_raw);
    int tn = (t < 64) ? (t + 1) : 64;
    phase_a(threadIdx.x, blockIdx.x, t, T, emb, W_ih, b_ih,
            HBUF(w, t), HBUF(w, tn), w.gh, w.slots, w.done, out, smem);
}

extern "C" void kernel_launch(void* const* d_in, const int* in_sizes, int n_in,
                              void* d_out, int out_size, void* d_ws, size_t ws_size,
                              hipStream_t stream) {
    const float* hidden = (const float*)d_in[0];
    const float* emb    = (const float*)d_in[1];
    const float* W_ih   = (const float*)d_in[2];
    const float* W_hh   = (const float*)d_in[3];
    const float* b_ih   = (const float*)d_in[4];
    const float* b_hh   = (const float*)d_in[5];
    const float* W_proj = (const float*)d_in[6];
    const float* b_proj = (const float*)d_in[7];
    const int* max_len  = (const int*)d_in[8];
    int* out = (int*)d_out;
    void* ws = d_ws;

    void* args[] = {&hidden, &emb, &W_ih, &W_hh, &b_ih, &b_hh,
                    &W_proj, &b_proj, &max_len, &out, &ws};
    hipError_t err = hipLaunchCooperativeKernel((const void*)decode_coop,
                                                dim3(NBLK), dim3(NTHR), args, 0, stream);
    if (err != hipSuccess) {
        (void)hipGetLastError();   // clear sticky error; deterministic fallback
        hipLaunchKernelGGL(k_init, dim3(16), dim3(NTHR), 0, stream, hidden, ws);
        hipLaunchKernelGGL(k_pre, dim3(NBLK), dim3(NTHR), 0, stream, W_hh, b_hh, ws);
        for (int t = 0; t <= 64; ++t) {
            hipLaunchKernelGGL(k_a, dim3(NBLK), dim3(NTHR), 0, stream,
                               t, max_len, emb, W_ih, b_ih, out, ws);
            if (t < 64)
                hipLaunchKernelGGL(k_b, dim3(NBLK), dim3(NTHR), 0, stream,
                                   t, max_len, W_proj, W_hh, b_proj, b_hh, ws);
        }
    }
}

// Round 10
// 6595.974 us; speedup vs baseline: 3.0285x; 3.0285x over previous
//
#include <hip/hip_runtime.h>
#include <math.h>

#define EOS_TOK 1
#define SOS_TOK 2
#define Bn 32
#define Hn 512
#define En 256
#define Vn 32000
#define G3H 1536
#define NBLK 256
#define NTHR 1024
#define VPB 125                  // V rows per block (256*125 = 32000 exact)
#define GPB 6                    // gh rows per block (256*6 = 1536 exact)
#define VT 5                     // 25 groups * 5 = 125 rows
#define CE 0.0085f               // rigorous bf16 logit error coefficient

typedef unsigned long long ull;
typedef unsigned int uint;

// ---- workspace layout (bytes) ----
#define WBF_OFF 0ull             // bf16 W_proj [32000][512]  (32,768,000)
#define WN_OFF  32768000ull      // row norms float[32000]
#define GH_OFF  32896000ull      // gh fp32 [32][1536]
#define ES_OFF  33092608ull      // exact slots [2][8][32] ull
#define LBS_OFF 33096704ull      // lb slots    [2][8][32] ull
#define DN_OFF  33100800ull      // done [2][32] int
#define H_OFF   33101056ull      // h fp32 [32][512]
#define LH_OFF  33166592ull      // fallback acc spill [256][1024][5] float

struct WS {
    unsigned short* wbf; float* wn; float* gh; ull* es; ull* lbs; int* done; float* h; float* lh;
};
__device__ __forceinline__ WS get_ws(void* p) {
    WS w;
    w.wbf = (unsigned short*)((char*)p + WBF_OFF);
    w.wn  = (float*)((char*)p + WN_OFF);
    w.gh  = (float*)((char*)p + GH_OFF);
    w.es  = (ull*)((char*)p + ES_OFF);
    w.lbs = (ull*)((char*)p + LBS_OFF);
    w.done= (int*)((char*)p + DN_OFF);
    w.h   = (float*)((char*)p + H_OFF);
    w.lh  = (float*)((char*)p + LH_OFF);
    return w;
}

// ---- relaxed agent-scope accessors (coherence-point, no cache maintenance) ----
template <typename T>
__device__ __forceinline__ T ldA(const T* p) {
    return __hip_atomic_load(p, __ATOMIC_RELAXED, __HIP_MEMORY_SCOPE_AGENT);
}
template <typename T>
__device__ __forceinline__ void stA(T* p, T v) {
    __hip_atomic_store(p, v, __ATOMIC_RELAXED, __HIP_MEMORY_SCOPE_AGENT);
}

// ---- fence-free grid barrier (proven R4+) ----
struct PadCnt { ull v; ull pad[7]; };
__device__ PadCnt g_leaf[32];
__device__ ull    g_release;

__device__ __forceinline__ void grid_barrier(int bid) {
    __syncthreads();
    if (threadIdx.x == 0) {
        __builtin_amdgcn_s_waitcnt(0);
        ull my = __hip_atomic_fetch_add(&g_leaf[bid >> 3].v, 1ull,
                                        __ATOMIC_RELAXED, __HIP_MEMORY_SCOPE_AGENT) + 1;
        ull k = (my + 7) >> 3;
        if (bid == 0) {
            ull need = k << 3;
            for (;;) {
                bool again = false;
                #pragma unroll
                for (int i = 0; i < 32; ++i) again |= (ldA(&g_leaf[i].v) < need);
                if (!again) break;
                __builtin_amdgcn_s_sleep(1);
            }
            stA(&g_release, k);
        } else {
            while (ldA(&g_release) < k) __builtin_amdgcn_s_sleep(2);
        }
        __asm__ __volatile__("" ::: "memory");
    }
    __syncthreads();
}

// ---- helpers ----
__device__ __forceinline__ uint fkey(float f) {
    uint b = __float_as_uint(f);
    return (b & 0x80000000u) ? ~b : (b | 0x80000000u);
}
__device__ __forceinline__ float ifkey(uint k) {
    uint b = (k & 0x80000000u) ? (k ^ 0x80000000u) : ~k;
    return __uint_as_float(b);
}
__device__ __forceinline__ uint f2bf(float f) {      // RN fp32->bf16
    uint u = __float_as_uint(f);
    return (u + 0x7FFFu + ((u >> 16) & 1u)) >> 16;
}
__device__ __forceinline__ float bflo(uint u) { return __uint_as_float(u << 16); }
__device__ __forceinline__ float bfhi(uint u) { return __uint_as_float(u & 0xFFFF0000u); }
__device__ __forceinline__ float ulo(ull u) { return __uint_as_float((uint)u); }
__device__ __forceinline__ float uhi(ull u) { return __uint_as_float((uint)(u >> 32)); }

// ---- LDS (disjoint regions, ~48 KB) ----
struct SM {
    uint4 h4[2048];              // 32 KB bf16 h-hat, [b][e8 ^ b]
    float hn[32];                // CE * ||h-hat||  (persists B1 -> C)
    float lbv[32];
    float ghsc[GPB * 32 * 6];    // gh partials [r6][b][ks]
    ull   red[32 * 32];
    int   cnt; int pad0[3];
    uint  list[256];
    int   tok[32];
    float gx[192];               // [ci][gate][b]
};

// ---- prologue work: h init + W bf16 conversion + row norms ----
__device__ void prologue(int tid, int bid, const float* __restrict__ hidden,
                         const float* __restrict__ W_proj, WS w)
{
    for (int i = bid * NTHR + tid; i < Bn * Hn / 2; i += NBLK * NTHR)
        stA((ull*)w.h + i, ((const ull*)hidden)[i]);
    for (int i = bid * NTHR + tid; i < Vn * Hn / 4; i += NBLK * NTHR) {
        float4 v = ((const float4*)W_proj)[i];
        ull o = (ull)(f2bf(v.x) | (f2bf(v.y) << 16))
              | ((ull)(f2bf(v.z) | (f2bf(v.w) << 16)) << 32);
        stA((ull*)w.wbf + i, o);
    }
    for (int r = bid * NTHR + tid; r < Vn; r += NBLK * NTHR) {
        const float4* wr = (const float4*)(W_proj + (size_t)r * Hn);
        float s0 = 0.f, s1 = 0.f;
        for (int e = 0; e < 128; e += 2) {
            float4 a = wr[e], b4 = wr[e + 1];
            s0 += a.x * a.x + a.z * a.z + b4.x * b4.x + b4.z * b4.z;
            s1 += a.y * a.y + a.w * a.w + b4.y * b4.y + b4.w * b4.w;
        }
        stA(&w.wn[r], sqrtf(s0 + s1) * 1.0005f);
    }
}

// ---- gh sub-phase: threads 832..1023 = 32 b x 6 k-splits, exact fp32 ----
__device__ void do_gh(int tid, int bid, const float* __restrict__ W_hh,
                      const float* __restrict__ h, SM* sm)
{
    if (tid < 832) return;
    int idx = tid - 832;                 // 0..191
    int b = idx & 31, ks = idx >> 5;     // ks in [0,6)
    int f40 = ks * 21 + (ks < 2 ? ks : 2);
    int nf4 = 21 + (ks < 2 ? 1 : 0);
    const ull* hp = (const ull*)h + b * 256 + f40 * 2;
    const float4* wr[GPB];
    #pragma unroll
    for (int r6 = 0; r6 < GPB; ++r6)
        wr[r6] = (const float4*)(W_hh + (size_t)(bid * GPB + r6) * Hn) + f40;
    float p[GPB];
    #pragma unroll
    for (int r6 = 0; r6 < GPB; ++r6) p[r6] = 0.f;
    for (int e = 0; e < nf4; ++e) {
        ull u0 = ldA(hp + 2 * e), u1 = ldA(hp + 2 * e + 1);
        float h0 = ulo(u0), h1 = uhi(u0), h2 = ulo(u1), h3 = uhi(u1);
        #pragma unroll
        for (int r6 = 0; r6 < GPB; ++r6) {
            float4 wv = wr[r6][e];
            p[r6] += wv.x * h0 + wv.y * h1 + wv.z * h2 + wv.w * h3;
        }
    }
    #pragma unroll
    for (int r6 = 0; r6 < GPB; ++r6)
        sm->ghsc[(r6 * 32 + b) * 6 + ks] = p[r6];
}
__device__ void fin_gh(int tid, int bid, const float* __restrict__ b_hh, float* __restrict__ gh, SM* sm)
{
    if (tid < 192) {
        int r6 = tid >> 5, b = tid & 31;
        float s = 0.f;
        #pragma unroll
        for (int j = 0; j < 6; ++j) s += sm->ghsc[(r6 * 32 + b) * 6 + j];
        int r = bid * GPB + r6;
        stA(&gh[(size_t)b * G3H + r], s + b_hh[r]);
    }
}

// ---- Phase B1: bf16 logits + bound, exact gh, lb-slot publish ----
__device__ void phase_b1(int tid, int bid, int t, WS w,
                         const float* __restrict__ W_hh, const float* __restrict__ b_hh,
                         const float* __restrict__ b_proj, SM* sm, float* acc, float* lh)
{
    // stage h-hat (bf16) into LDS, swizzled
    for (int i = tid; i < 2048; i += NTHR) {
        int bb = i >> 6, e8 = i & 63;
        const ull* hs = (const ull*)w.h + bb * 256 + e8 * 4;
        ull a = ldA(hs), b2 = ldA(hs + 1), c = ldA(hs + 2), d = ldA(hs + 3);
        uint4 P;
        P.x = f2bf(ulo(a))  | (f2bf(uhi(a))  << 16);
        P.y = f2bf(ulo(b2)) | (f2bf(uhi(b2)) << 16);
        P.z = f2bf(ulo(c))  | (f2bf(uhi(c))  << 16);
        P.w = f2bf(ulo(d))  | (f2bf(uhi(d))  << 16);
        sm->h4[(bb << 6) + (e8 ^ bb)] = P;
    }
    __syncthreads();

    do_gh(tid, bid, W_hh, w.h, sm);                  // waves 13-15

    if (tid >= 800 && tid < 832) {                   // norm group (half of wave 12)
        int b = tid & 31;
        float s = 0.f;
        for (int e8 = 0; e8 < 64; ++e8) {
            uint4 H = sm->h4[(b << 6) + (e8 ^ b)];
            float f0=bflo(H.x),f1=bfhi(H.x),f2=bflo(H.y),f3=bfhi(H.y);
            float f4=bflo(H.z),f5=bfhi(H.z),f6=bflo(H.w),f7=bfhi(H.w);
            s += f0*f0+f1*f1+f2*f2+f3*f3+f4*f4+f5*f5+f6*f6+f7*f7;
        }
        sm->hn[b] = CE * sqrtf(s);
    }

    const int g = tid >> 5, b = tid & 31;
    const bool isv = g < 25;
    const int rbase = bid * VPB + g * VT;
    #pragma unroll
    for (int i = 0; i < VT; ++i) acc[i] = 0.f;
    if (isv) {
        const uint4* wp = (const uint4*)w.wbf + (size_t)rbase * 64;
        float ax[VT], ay[VT];
        #pragma unroll
        for (int i = 0; i < VT; ++i) { ax[i] = 0.f; ay[i] = 0.f; }
        #pragma unroll 2
        for (int e8 = 0; e8 < 64; ++e8) {
            uint4 H = sm->h4[(b << 6) + (e8 ^ b)];
            float h0=bflo(H.x),h1=bfhi(H.x),h2=bflo(H.y),h3=bfhi(H.y);
            float h4=bflo(H.z),h5=bfhi(H.z),h6=bflo(H.w),h7=bfhi(H.w);
            #pragma unroll
            for (int i = 0; i < VT; ++i) {
                uint4 U = wp[i * 64 + e8];
                ax[i] += bflo(U.x) * h0; ay[i] += bfhi(U.x) * h1;
                ax[i] += bflo(U.y) * h2; ay[i] += bfhi(U.y) * h3;
                ax[i] += bflo(U.z) * h4; ay[i] += bfhi(U.z) * h5;
                ax[i] += bflo(U.w) * h6; ay[i] += bfhi(U.w) * h7;
            }
        }
        #pragma unroll
        for (int i = 0; i < VT; ++i) acc[i] = ax[i] + ay[i];
    }
    __syncthreads();                                 // hn + ghsc ready, h4 reads done

    fin_gh(tid, bid, b_hh, w.gh, sm);

    ull pk = 0ull;
    if (isv) {
        float hnb = sm->hn[b];
        #pragma unroll
        for (int i = 0; i < VT; ++i) {
            int r = rbase + i;
            float L = acc[i] + b_proj[r];
            float E = hnb * w.wn[r];
            ull q = ((ull)fkey(L - E)) << 32;
            if (q > pk) pk = q;
        }
        if (lh) {
            #pragma unroll
            for (int i = 0; i < VT; ++i)
                lh[((size_t)bid * NTHR + tid) * VT + i] = acc[i];
        }
    }
    sm->red[g * 32 + b] = pk;
    __syncthreads();
    if (tid < Bn) {
        ull m = sm->red[tid];
        #pragma unroll
        for (int s = 1; s < 32; ++s) {
            ull v = sm->red[s * 32 + tid];
            if (v > m) m = v;
        }
        if (m != 0ull)
            atomicMax(&w.lbs[((size_t)(t & 1) * 8 + (bid & 7)) * Bn + tid], m);
    }
}

// ---- Phase C: candidate selection + exact fp32 recheck ----
__device__ void phase_c(int tid, int bid, int t, WS w,
                        const float* __restrict__ W_proj, const float* __restrict__ b_proj,
                        SM* sm, float* acc, bool standalone)
{
    const int g = tid >> 5, b = tid & 31, lane = tid & 63, wv = tid >> 6;
    if (standalone && tid < Bn) {                    // fallback path: recompute hn
        const ull* hp = (const ull*)w.h + tid * 256;
        float s = 0.f;
        for (int e = 0; e < 256; ++e) {
            ull u = ldA(hp + e);
            float a = ulo(u), c = uhi(u);
            s += a * a + c * c;
        }
        sm->hn[tid] = CE * sqrtf(s);
    }
    if (tid < Bn) {
        const ull* sl = w.lbs + (size_t)(t & 1) * (8 * Bn);
        ull m = ldA(&sl[tid]);
        #pragma unroll
        for (int s = 1; s < 8; ++s) {
            ull v = ldA(&sl[s * Bn + tid]);
            if (v > m) m = v;
        }
        sm->lbv[tid] = ifkey((uint)(m >> 32));
    }
    if (tid == 0) sm->cnt = 0;
    __syncthreads();
    if (g < 25) {
        float hnb = sm->hn[b], lb = sm->lbv[b];
        int rbase = bid * VPB + g * VT;
        #pragma unroll
        for (int i = 0; i < VT; ++i) {
            int r = rbase + i;
            float L = acc[i] + b_proj[r];
            float E = hnb * w.wn[r];
            if (L + E >= lb) {
                int ix = atomicAdd(&sm->cnt, 1);
                if (ix < 256) sm->list[ix] = (uint)((r << 5) | b);
            }
        }
    }
    __syncthreads();
    int nc = sm->cnt; if (nc > 256) nc = 256;
    for (int wi = wv; wi < nc; wi += 16) {
        uint e = sm->list[wi];
        int r = (int)(e >> 5), bb = (int)(e & 31);
        const float4* wr = (const float4*)(W_proj + (size_t)r * Hn) + lane * 2;
        float4 wA = wr[0], wB = wr[1];
        const ull* hp = (const ull*)w.h + bb * 256 + lane * 4;
        ull u0 = ldA(hp), u1 = ldA(hp + 1), u2 = ldA(hp + 2), u3 = ldA(hp + 3);
        float s = wA.x*ulo(u0) + wA.y*uhi(u0) + wA.z*ulo(u1) + wA.w*uhi(u1)
                + wB.x*ulo(u2) + wB.y*uhi(u2) + wB.z*ulo(u3) + wB.w*uhi(u3);
        #pragma unroll
        for (int d = 1; d < 64; d <<= 1) s += __shfl_xor(s, d);
        if (lane == 0) {
            s += b_proj[r];
            ull q = ((ull)fkey(s) << 32) | (uint)(~(uint)r);
            atomicMax(&w.es[((size_t)(t & 1) * 8 + (bid & 7)) * Bn + bb], q);
        }
    }
}

// ---- Phase A: token resolve + embed/gx + gate combine + h update ----
__device__ void phase_a(int tid, int bid, int t, int T,
                        const float* __restrict__ emb, const float* __restrict__ W_ih,
                        const float* __restrict__ b_ih, WS w, int* __restrict__ out, SM* sm)
{
    if (tid < Bn) {
        int b = tid, tok, dnew;
        if (t == 0) { tok = SOS_TOK; dnew = 0; }
        else {
            const ull* sl = w.es + (size_t)((t - 1) & 1) * (8 * Bn);
            ull m = ldA(&sl[b]);
            #pragma unroll
            for (int s = 1; s < 8; ++s) {
                ull v = ldA(&sl[s * Bn + b]);
                if (v > m) m = v;
            }
            int idx = (int)(~(uint)m);
            int dold = ldA(&w.done[((t - 1) & 1) * Bn + b]);
            tok = dold ? EOS_TOK : idx;
            dnew = dold | (idx == EOS_TOK);
        }
        sm->tok[b] = tok;
        if (bid == 0) {
            stA(&w.done[(t & 1) * Bn + b], dnew);
            if (t > 0) out[(size_t)(t - 1) * Bn + b] = tok;
            ull* s1 = w.es  + (size_t)(t & 1) * (8 * Bn);
            ull* s2 = w.lbs + (size_t)(t & 1) * (8 * Bn);
            #pragma unroll
            for (int s = 0; s < 8; ++s) { stA(&s1[s * Bn + b], 0ull); stA(&s2[s * Bn + b], 0ull); }
        }
    }
    __syncthreads();
    if (t >= T) return;

    if (tid < 768) {
        int d = tid >> 2, q = tid & 3;
        int b = d & 31, rem = d >> 5, gate = rem >> 1, ci = rem & 1;
        int col = bid + (ci << 8);
        const float* wrow = W_ih + (size_t)(gate * Hn + col) * En + q * (En / 4);
        const float* xrow = emb + (size_t)sm->tok[b] * En + q * (En / 4);
        float ax = 0.f, ay = 0.f;
        #pragma unroll
        for (int e4 = 0; e4 < En / 16; ++e4) {
            float4 w4 = *(const float4*)(wrow + 4 * e4);
            float4 x4 = *(const float4*)(xrow + 4 * e4);
            ax = fmaf(x4.x, w4.x, ax); ay = fmaf(x4.y, w4.y, ay);
            ax = fmaf(x4.z, w4.z, ax); ay = fmaf(x4.w, w4.w, ay);
        }
        float a = ax + ay;
        a += __shfl_xor(a, 1);
        a += __shfl_xor(a, 2);
        if (q == 0) sm->gx[(ci * 3 + gate) * 32 + b] = a;
    }
    __syncthreads();

    if (tid < 64) {
        int b = tid & 31, ci = tid >> 5;
        int col = bid + (ci << 8);
        float gxr = sm->gx[(ci * 3 + 0) * 32 + b] + b_ih[col];
        float gxz = sm->gx[(ci * 3 + 1) * 32 + b] + b_ih[Hn + col];
        float gxn = sm->gx[(ci * 3 + 2) * 32 + b] + b_ih[2 * Hn + col];
        const float* ghrow = w.gh + (size_t)b * G3H;
        float ghr = ldA(&ghrow[col]);
        float ghz = ldA(&ghrow[Hn + col]);
        float ghn = ldA(&ghrow[2 * Hn + col]);
        float r = 1.0f / (1.0f + expf(-(gxr + ghr)));
        float z = 1.0f / (1.0f + expf(-(gxz + ghz)));
        float n = tanhf(gxn + r * ghn);
        float* hp = w.h + (size_t)b * Hn + col;
        float hold = ldA(hp);
        stA(hp, (1.0f - z) * n + z * hold);
    }
}

// ================= cooperative single-kernel path =================
__global__ void __launch_bounds__(NTHR, 4)
decode_coop(const float* __restrict__ hidden, const float* __restrict__ emb,
            const float* __restrict__ W_ih, const float* __restrict__ W_hh,
            const float* __restrict__ b_ih, const float* __restrict__ b_hh,
            const float* __restrict__ W_proj, const float* __restrict__ b_proj,
            const int* __restrict__ max_len_p, int* __restrict__ out, void* ws_raw)
{
    const int tid = threadIdx.x, bid = blockIdx.x;
    __shared__ SM sm;
    WS w = get_ws(ws_raw);
    const int T = max_len_p[0];

    prologue(tid, bid, hidden, W_proj, w);
    grid_barrier(bid);
    do_gh(tid, bid, W_hh, w.h, &sm);                 // gh(h0)
    __syncthreads();
    fin_gh(tid, bid, b_hh, w.gh, &sm);
    grid_barrier(bid);

    for (int t = 0; t < T; ++t) {
        phase_a(tid, bid, t, T, emb, W_ih, b_ih, w, out, &sm);
        grid_barrier(bid);
        float acc[VT];
        phase_b1(tid, bid, t, w, W_hh, b_hh, b_proj, &sm, acc, nullptr);
        grid_barrier(bid);
        phase_c(tid, bid, t, w, W_proj, b_proj, &sm, acc, false);
        grid_barrier(bid);
    }
    phase_a(tid, bid, T, T, emb, W_ih, b_ih, w, out, &sm);
}

// ================= non-cooperative fallback path =================
__global__ void __launch_bounds__(NTHR, 4)
k_pro(const float* __restrict__ hidden, const float* __restrict__ W_proj, void* ws_raw) {
    WS w = get_ws(ws_raw);
    prologue(threadIdx.x, blockIdx.x, hidden, W_proj, w);
}
__global__ void __launch_bounds__(NTHR, 4)
k_pre(const float* __restrict__ W_hh, const float* __restrict__ b_hh, void* ws_raw) {
    __shared__ SM sm;
    WS w = get_ws(ws_raw);
    do_gh(threadIdx.x, blockIdx.x, W_hh, w.h, &sm);
    __syncthreads();
    fin_gh(threadIdx.x, blockIdx.x, b_hh, w.gh, &sm);
}
__global__ void __launch_bounds__(NTHR, 4)
k_a(int t, const int* __restrict__ max_len_p,
    const float* __restrict__ emb, const float* __restrict__ W_ih,
    const float* __restrict__ b_ih, int* __restrict__ out, void* ws_raw)
{
    int T = max_len_p[0];
    if (t > T) return;
    __shared__ SM sm;
    WS w = get_ws(ws_raw);
    phase_a(threadIdx.x, blockIdx.x, t, T, emb, W_ih, b_ih, w, out, &sm);
}
__global__ void __launch_bounds__(NTHR, 4)
k_b1(int t, const int* __restrict__ max_len_p,
     const float* __restrict__ W_hh, const float* __restrict__ b_hh,
     const float* __restrict__ b_proj, void* ws_raw)
{
    if (t >= max_len_p[0]) return;
    __shared__ SM sm;
    WS w = get_ws(ws_raw);
    float acc[VT];
    phase_b1(threadIdx.x, blockIdx.x, t, w, W_hh, b_hh, b_proj, &sm, acc, w.lh);
}
__global__ void __launch_bounds__(NTHR, 4)
k_c(int t, const int* __restrict__ max_len_p,
    const float* __restrict__ W_proj, const float* __restrict__ b_proj, void* ws_raw)
{
    if (t >= max_len_p[0]) return;
    __shared__ SM sm;
    WS w = get_ws(ws_raw);
    float acc[VT];
    #pragma unroll
    for (int i = 0; i < VT; ++i)
        acc[i] = w.lh[((size_t)blockIdx.x * NTHR + threadIdx.x) * VT + i];
    phase_c(threadIdx.x, blockIdx.x, t, w, W_proj, b_proj, &sm, acc, true);
}

extern "C" void kernel_launch(void* const* d_in, const int* in_sizes, int n_in,
                              void* d_out, int out_size, void* d_ws, size_t ws_size,
                              hipStream_t stream) {
    const float* hidden = (const float*)d_in[0];
    const float* emb    = (const float*)d_in[1];
    const float* W_ih   = (const float*)d_in[2];
    const float* W_hh   = (const float*)d_in[3];
    const float* b_ih   = (const float*)d_in[4];
    const float* b_hh   = (const float*)d_in[5];
    const float* W_proj = (const float*)d_in[6];
    const float* b_proj = (const float*)d_in[7];
    const int* max_len  = (const int*)d_in[8];
    int* out = (int*)d_out;
    void* ws = d_ws;

    void* args[] = {&hidden, &emb, &W_ih, &W_hh, &b_ih, &b_hh,
                    &W_proj, &b_proj, &max_len, &out, &ws};
    hipError_t err = hipLaunchCooperativeKernel((const void*)decode_coop,
                                                dim3(NBLK), dim3(NTHR), args, 0, stream);
    if (err != hipSuccess) {
        (void)hipGetLastError();   // deterministic fallback chain
        hipLaunchKernelGGL(k_pro, dim3(NBLK), dim3(NTHR), 0, stream, hidden, W_proj, ws);
        hipLaunchKernelGGL(k_pre, dim3(NBLK), dim3(NTHR), 0, stream, W_hh, b_hh, ws);
        for (int t = 0; t <= 64; ++t) {
            hipLaunchKernelGGL(k_a, dim3(NBLK), dim3(NTHR), 0, stream,
                               t, max_len, emb, W_ih, b_ih, out, ws);
            if (t < 64) {
                hipLaunchKernelGGL(k_b1, dim3(NBLK), dim3(NTHR), 0, stream,
                                   t, max_len, W_hh, b_hh, b_proj, ws);
                hipLaunchKernelGGL(k_c, dim3(NBLK), dim3(NTHR), 0, stream,
                                   t, max_len, W_proj, b_proj, ws);
            }
        }
    }
}